// Round 1
// baseline (5751.806 us; speedup 1.0000x reference)
//
#include <hip/hip_runtime.h>

// ---------------------------------------------------------------------------
// ViT forward on MI355X (gfx950). Round 5:
//  - gemm3_k: BM=128 BN=128 BK=64 (m97-class geometry), double-buffered
//    global_load_lds staging, XOR-swizzled LDS (slot ^= row&7) on both the
//    pre-swizzled global source and the ds_read side -> bank-conflict-free.
//  - all GEMMs (patch/MLP1/MLP2/head) via gemm3_k
// ---------------------------------------------------------------------------

typedef __bf16 v8bf __attribute__((ext_vector_type(8)));
typedef __bf16 v4bf __attribute__((ext_vector_type(4)));
typedef float  v4f  __attribute__((ext_vector_type(4)));

#define DEV static __device__ __forceinline__

DEV v8bf cvt8(float4 a, float4 b) {
    v8bf r;
    r[0]=(__bf16)a.x; r[1]=(__bf16)a.y; r[2]=(__bf16)a.z; r[3]=(__bf16)a.w;
    r[4]=(__bf16)b.x; r[5]=(__bf16)b.y; r[6]=(__bf16)b.z; r[7]=(__bf16)b.w;
    return r;
}
DEV v8bf bzero8() {
    v8bf z;
    #pragma unroll
    for (int i=0;i<8;i++) z[i]=(__bf16)0.f;
    return z;
}
DEV v4f fzero4() {
    v4f z;
    #pragma unroll
    for (int i=0;i<4;i++) z[i]=0.f;
    return z;
}
// async global->LDS, 16 bytes per lane; LDS dest = l + lane*16 (wave-uniform base)
DEV void async16(const __bf16* g, __bf16* l) {
    __builtin_amdgcn_global_load_lds(
        (const __attribute__((address_space(1))) void*)g,
        (__attribute__((address_space(3))) void*)l,
        16, 0, 0);
}

// ---------------------------------------------------------------------------
// fp32 -> bf16 elementwise (n4 = count/4)
__global__ void f2b_k(const float* __restrict__ s, __bf16* __restrict__ d, int n4) {
    int i = blockIdx.x*256 + threadIdx.x;
    if (i >= n4) return;
    float4 f = ((const float4*)s)[i];
    v4bf b;
    b[0]=(__bf16)f.x; b[1]=(__bf16)f.y; b[2]=(__bf16)f.z; b[3]=(__bf16)f.w;
    ((v4bf*)d)[i] = b;
}

// ---------------------------------------------------------------------------
// pre-fill residual with pos-embed (+cls on token 0).
__global__ void pos_init_k(const float* __restrict__ cls, float* __restrict__ resid) {
    int idx = blockIdx.x*256 + threadIdx.x;   // 9,682,944 exact
    int col = idx % 768; int rt = idx / 768;
    int ti = rt % 197;
    float v;
    if (ti == 0) v = cls[col];
    else {
        float e = (ti & 1) ? (float)(col - 1) : (float)col;
        float wj = expf(e * -0.011992630692677323f);   // ln(1e4)/768
        v = (ti & 1) ? cosf(ti*wj) : sinf(ti*wj);
    }
    resid[idx] = v;
}

// zero the vT padding (s in [197,208)) — ws is re-poisoned before each call
__global__ void vpad_k(__bf16* __restrict__ vT) {
    int idx = blockIdx.x*256 + threadIdx.x;   // 540,672 exact
    int a = idx/11, s = idx - a*11;
    vT[(size_t)a*208 + 197 + s] = (__bf16)0.f;
}

// ---------------------------------------------------------------------------
// patchify: x (64,3,224,224) fp32 -> Apat (12544,768) bf16
__global__ void patchify_k(const float* __restrict__ x, __bf16* __restrict__ Ap) {
    int idx = blockIdx.x*256 + threadIdx.x;   // 12544*768 exact
    int m = idx/768, kk = idx - m*768;
    int n = m/196, pp = m - n*196;
    int pi = pp/14, pj = pp - pi*14;
    int c = kk >> 8, rr = kk & 255, hi = rr >> 4, wi = rr & 15;
    Ap[idx] = (__bf16)x[((size_t)((n*3 + c)*224 + pi*16 + hi))*224 + pj*16 + wi];
}

// extract: residual token-0 rows -> Ahead (64,768) bf16
__global__ void extract_k(const float* __restrict__ resid, __bf16* __restrict__ Ah) {
    int idx = blockIdx.x*256 + threadIdx.x;   // 49152 exact
    int n = idx/768, d = idx - n*768;
    Ah[idx] = (__bf16)resid[(size_t)(n*197)*768 + d];
}

// ---------------------------------------------------------------------------
// LayerNorm over D=768: fp32 in -> bf16 out. One block per row.
__global__ __launch_bounds__(256) void ln_k(const float* __restrict__ resid,
                                            const float* __restrict__ gamma,
                                            const float* __restrict__ beta,
                                            __bf16* __restrict__ out) {
    __shared__ float red[4];
    int row = blockIdx.x, t = threadIdx.x;
    const float* xr = resid + (size_t)row*768;
    float x0 = xr[t], x1 = xr[t+256], x2 = xr[t+512];
    float s = x0+x1+x2;
    #pragma unroll
    for (int off=1; off<64; off<<=1) s += __shfl_xor(s, off, 64);
    if ((t&63)==0) red[t>>6] = s;
    __syncthreads();
    float mu = (red[0]+red[1]+red[2]+red[3]) * (1.f/768.f);
    __syncthreads();
    float d0=x0-mu, d1=x1-mu, d2=x2-mu;
    float q = d0*d0 + d1*d1 + d2*d2;
    #pragma unroll
    for (int off=1; off<64; off<<=1) q += __shfl_xor(q, off, 64);
    if ((t&63)==0) red[t>>6] = q;
    __syncthreads();
    float var = (red[0]+red[1]+red[2]+red[3]) * (1.f/768.f);
    float rs = rsqrtf(var + 1e-5f);
    __bf16* o = out + (size_t)row*768;
    o[t]     = (__bf16)(d0*rs*gamma[t]     + beta[t]);
    o[t+256] = (__bf16)(d1*rs*gamma[t+256] + beta[t+256]);
    o[t+512] = (__bf16)(d2*rs*gamma[t+512] + beta[t+512]);
}

// ---------------------------------------------------------------------------
// GEMM: C[m][n] = sum_k A[m][k]*B[n][k], A,B bf16. Tile 128x128x64, dbuf LDS,
// XOR-swizzled (slot ^= row&7 in 16B slots; source pre-swizzled since
// global_load_lds writes linearly). 256 threads = 4 waves in 2x2; each wave
// 64x64 output (4x4 MFMA tiles, 64 acc VGPRs).
// EPI: 0 = +bias, patch-embed row remap (n*197+p+1), += into resid
//      1 = +bias, GELU -> bf16
//      2 = +bias, += resid fp32
//      3 = +bias -> fp32 out
template<int EPI>
__global__ __launch_bounds__(256) void gemm3_k(
    const __bf16* __restrict__ A, const __bf16* __restrict__ B,
    const float* __restrict__ bias,
    float* __restrict__ outf, __bf16* __restrict__ outb,
    int M, int N, int K, int MV, int NV)
{
    __shared__ __align__(16) __bf16 As[2][128*64];
    __shared__ __align__(16) __bf16 Bs[2][128*64];
    const int tid = threadIdx.x, lane = tid & 63, w = tid >> 6;
    const int m0 = blockIdx.y * 128, n0 = blockIdx.x * 128;
    const int rw = (w & 1) * 64, cw = (w >> 1) * 64;
    const int lg = lane >> 4, lc = lane & 15;
    const int lr = lane >> 3;
    const int lk8s = (((lane & 7) ^ lr) * 8);  // pre-swizzled source 16B slot

    v4f acc[4][4];
    #pragma unroll
    for (int i=0;i<4;i++)
        #pragma unroll
        for (int j=0;j<4;j++) acc[i][j] = fzero4();

    const int NK = K >> 6;
    // stage: A 16 chunks (4/wave), B 16 chunks (4/wave); chunk = 8 rows of 64.
    // LDS dest is linear (lane*16B); global source column is XOR-swizzled so
    // that physical slot p of row r holds logical slot p^(r&7).
    auto stage = [&](int buf, int kt) {
        #pragma unroll
        for (int i=0;i<4;i++) {
            int chunk = w*4 + i;
            int r = chunk*8 + lr;
            int gr = m0 + r; gr = gr < M ? gr : M-1;
            async16(A + (size_t)gr*K + kt + lk8s, &As[buf][chunk*512]);
        }
        #pragma unroll
        for (int i=0;i<4;i++) {
            int chunk = w*4 + i;
            int r = chunk*8 + lr;
            int gc = n0 + r; gc = gc < N ? gc : N-1;
            async16(B + (size_t)gc*K + kt + lk8s, &Bs[buf][chunk*512]);
        }
    };

    stage(0, 0);
    for (int ki = 0; ki < NK; ki++) {
        __syncthreads();              // drains vmcnt: buf[ki&1] ready, prev reads done
        if (ki + 1 < NK) stage((ki+1) & 1, (ki+1) << 6);
        const __bf16* as = As[ki & 1];
        const __bf16* bs = Bs[ki & 1];
        #pragma unroll
        for (int ks=0; ks<2; ks++) {
            v8bf af[4], bf[4];
            #pragma unroll
            for (int i=0;i<4;i++) {
                int row = rw + i*16 + lc;
                af[i] = *(const v8bf*)&as[row*64 + (((ks*4 + lg) ^ (row & 7)) << 3)];
            }
            #pragma unroll
            for (int j=0;j<4;j++) {
                int row = cw + j*16 + lc;
                bf[j] = *(const v8bf*)&bs[row*64 + (((ks*4 + lg) ^ (row & 7)) << 3)];
            }
            #pragma unroll
            for (int i=0;i<4;i++)
                #pragma unroll
                for (int j=0;j<4;j++)
                    acc[i][j] = __builtin_amdgcn_mfma_f32_16x16x32_bf16(
                        af[i], bf[j], acc[i][j], 0, 0, 0);
        }
    }

    #pragma unroll
    for (int i=0;i<4;i++)
        #pragma unroll
        for (int j=0;j<4;j++)
            #pragma unroll
            for (int r=0;r<4;r++) {
                int row = m0 + rw + i*16 + lg*4 + r;
                int col = n0 + cw + j*16 + lc;
                if (row >= MV || col >= NV) continue;
                float v = acc[i][j][r];
                if constexpr (EPI == 0) {
                    int n = row / 196, p = row - n*196;
                    outf[((size_t)(n*197 + p + 1))*768 + col] += v + bias[col];
                } else if constexpr (EPI == 1) {
                    float tt = v + bias[col];
                    outb[(size_t)row*NV + col] =
                        (__bf16)(0.5f*tt*(1.f + erff(tt*0.70710678118654752f)));
                } else if constexpr (EPI == 2) {
                    outf[(size_t)row*NV + col] += v + bias[col];
                } else {
                    outf[(size_t)row*NV + col] = v + bias[col];
                }
            }
}

// ---------------------------------------------------------------------------
// Per-head QKV projection. Grid (197 m-tiles of 64, 12 heads).
__global__ __launch_bounds__(256) void qkv_k(
    const __bf16* __restrict__ xln,
    const float* __restrict__ Wq, const float* __restrict__ bq,
    const float* __restrict__ Wk, const float* __restrict__ bk,
    const float* __restrict__ Wv, const float* __restrict__ bv,
    __bf16* __restrict__ qo, __bf16* __restrict__ ko, __bf16* __restrict__ vT,
    int l)
{
    constexpr int LDT = 72;
    __shared__ __align__(16) __bf16 Xs[64*LDT];
    __shared__ __align__(16) __bf16 Ws[3*64*LDT];
    const int tid = threadIdx.x, lane = tid & 63, w = tid >> 6;
    const int lg = lane >> 4, lc = lane & 15;
    const int m0 = blockIdx.x * 64, h = blockIdx.y;
    const int off = (l*12 + h) * 4096, bo = (l*12 + h) * 64;
    const float* Wm[3] = {Wq + off, Wk + off, Wv + off};
    const float* Bm[3] = {bq + bo, bk + bo, bv + bo};

    #pragma unroll
    for (int i=0;i<2;i++) {
        int c = i*256 + tid, r = c >> 3, k8 = (c & 7) * 8;
        *(v8bf*)&Xs[r*LDT + k8] = *(const v8bf*)(xln + (size_t)(m0+r)*768 + h*64 + k8);
    }
    #pragma unroll
    for (int mat=0; mat<3; mat++)
        #pragma unroll
        for (int i=0;i<2;i++) {
            int c = i*256 + tid, r = c >> 3, k8 = (c & 7) * 8;
            const float* p = Wm[mat] + r*64 + k8;
            *(v8bf*)&Ws[mat*64*LDT + r*LDT + k8] =
                cvt8(*(const float4*)p, *(const float4*)(p+4));
        }
    __syncthreads();

    v8bf af[2];
    af[0] = *(const v8bf*)&Xs[(w*16 + lc)*LDT + lg*8];
    af[1] = *(const v8bf*)&Xs[(w*16 + lc)*LDT + 32 + lg*8];
    v4f acc[3][4];
    #pragma unroll
    for (int m=0;m<3;m++)
        #pragma unroll
        for (int j=0;j<4;j++) acc[m][j] = fzero4();

    #pragma unroll
    for (int mat=0; mat<3; mat++)
        #pragma unroll
        for (int ks=0; ks<2; ks++)
            #pragma unroll
            for (int nt=0; nt<4; nt++) {
                v8bf bf = *(const v8bf*)&Ws[mat*64*LDT + (nt*16 + lc)*LDT + ks*32 + lg*8];
                acc[mat][nt] = __builtin_amdgcn_mfma_f32_16x16x32_bf16(
                    af[ks], bf, acc[mat][nt], 0, 0, 0);
            }

    #pragma unroll
    for (int mat=0; mat<3; mat++)
        #pragma unroll
        for (int nt=0; nt<4; nt++)
            #pragma unroll
            for (int r=0; r<4; r++) {
                int row = m0 + w*16 + lg*4 + r;
                int n = row / 197, s = row - n*197;
                int o = nt*16 + lc;
                float v = acc[mat][nt][r] + Bm[mat][o];
                if (mat == 0)
                    qo[(size_t)((n*12 + h)*197 + s)*64 + o] = (__bf16)v;
                else if (mat == 1)
                    ko[(size_t)((n*12 + h)*197 + s)*64 + o] = (__bf16)v;
                else
                    vT[(size_t)((n*12 + h)*64 + o)*208 + s] = (__bf16)v;
            }
}

// ---------------------------------------------------------------------------
// Attention for one (n,h,qtile-of-64). S=197 padded to 224 keys.
__global__ __launch_bounds__(256) void attn_k(
    const __bf16* __restrict__ q, const __bf16* __restrict__ k,
    const __bf16* __restrict__ vT, float* __restrict__ resid)
{
    __shared__ __align__(16) __bf16 KP[224*72];    // K tile, later aliased as P
    __shared__ __align__(16) __bf16 Vsh[64*232];   // V^T tile [dh][key]
    const int tid = threadIdx.x, lane = tid & 63, w = tid >> 6;
    const int lg = lane >> 4, lc = lane & 15;
    const int q0 = blockIdx.x * 64, h = blockIdx.y, n = blockIdx.z;
    const size_t nh = n*12 + h;
    const __bf16* kg = k  + nh*197*64;
    const __bf16* vg = vT + nh*64*208;
    const __bf16* qg = q  + nh*197*64;
    const v8bf z8 = bzero8();

    #pragma unroll
    for (int i=0;i<7;i++) {
        int c = i*256 + tid, r = c >> 3, k8 = (c & 7) * 8;
        v8bf val = (r < 197) ? *(const v8bf*)(kg + r*64 + k8) : z8;
        *(v8bf*)&KP[r*72 + k8] = val;
    }
    #pragma unroll
    for (int i=0;i<7;i++) {
        int c = i*256 + tid, r = c/28, s8 = (c - r*28) * 8;
        v8bf val = (s8 < 208) ? *(const v8bf*)(vg + r*208 + s8) : z8;
        *(v8bf*)&Vsh[r*232 + s8] = val;
    }
    int qs = q0 + w*16 + lc; qs = qs < 197 ? qs : 196;
    v8bf aq0 = *(const v8bf*)(qg + qs*64 + lg*8);
    v8bf aq1 = *(const v8bf*)(qg + qs*64 + 32 + lg*8);
    __syncthreads();

    v4f sc[14];
    #pragma unroll
    for (int nt=0; nt<14; nt++) sc[nt] = fzero4();
    #pragma unroll
    for (int nt=0; nt<14; nt++) {
        v8bf b0 = *(const v8bf*)&KP[(nt*16 + lc)*72 + lg*8];
        v8bf b1 = *(const v8bf*)&KP[(nt*16 + lc)*72 + 32 + lg*8];
        sc[nt] = __builtin_amdgcn_mfma_f32_16x16x32_bf16(aq0, b0, sc[nt], 0,0,0);
        sc[nt] = __builtin_amdgcn_mfma_f32_16x16x32_bf16(aq1, b1, sc[nt], 0,0,0);
    }
    __syncthreads();

    #pragma unroll
    for (int r=0; r<4; r++) {
        float mx = -1e30f;
        #pragma unroll
        for (int nt=0; nt<14; nt++)
            if (nt*16 + lc < 197) mx = fmaxf(mx, sc[nt][r]);
        #pragma unroll
        for (int off=1; off<16; off<<=1) mx = fmaxf(mx, __shfl_xor(mx, off, 64));
        float sm = 0.f;
        #pragma unroll
        for (int nt=0; nt<14; nt++) {
            float p = (nt*16 + lc < 197) ? expf((sc[nt][r] - mx) * 0.125f) : 0.f;
            sc[nt][r] = p; sm += p;
        }
        #pragma unroll
        for (int off=1; off<16; off<<=1) sm += __shfl_xor(sm, off, 64);
        float inv = 1.f / sm;
        int prow = w*16 + lg*4 + r;
        #pragma unroll
        for (int nt=0; nt<14; nt++)
            KP[prow*232 + nt*16 + lc] = (__bf16)(sc[nt][r] * inv);
    }

    v4f ov[4];
    #pragma unroll
    for (int nt=0; nt<4; nt++) ov[nt] = fzero4();
    #pragma unroll
    for (int ks=0; ks<7; ks++) {
        v8bf a = *(const v8bf*)&KP[(w*16 + lc)*232 + ks*32 + lg*8];
        #pragma unroll
        for (int nt=0; nt<4; nt++) {
            v8bf b = *(const v8bf*)&Vsh[(nt*16 + lc)*232 + ks*32 + lg*8];
            ov[nt] = __builtin_amdgcn_mfma_f32_16x16x32_bf16(a, b, ov[nt], 0,0,0);
        }
    }
    #pragma unroll
    for (int nt=0; nt<4; nt++)
        #pragma unroll
        for (int r=0; r<4; r++) {
            int qrow = q0 + w*16 + lg*4 + r;
            if (qrow < 197) {
                float* p = resid + ((size_t)n*197 + qrow)*768 + h*64 + nt*16 + lc;
                *p += ov[nt][r];
            }
        }
}

// ---------------------------------------------------------------------------
extern "C" void kernel_launch(void* const* d_in, const int* in_sizes, int n_in,
                              void* d_out, int out_size, void* d_ws, size_t ws_size,
                              hipStream_t stream) {
    const float* x    = (const float*)d_in[0];
    const float* Wp   = (const float*)d_in[1];
    const float* bp   = (const float*)d_in[2];
    const float* cls  = (const float*)d_in[3];
    const float* ln1g = (const float*)d_in[4];
    const float* ln1b = (const float*)d_in[5];
    const float* Wq   = (const float*)d_in[6];
    const float* bq   = (const float*)d_in[7];
    const float* Wk   = (const float*)d_in[8];
    const float* bk   = (const float*)d_in[9];
    const float* Wv   = (const float*)d_in[10];
    const float* bv   = (const float*)d_in[11];
    const float* ln2g = (const float*)d_in[12];
    const float* ln2b = (const float*)d_in[13];
    const float* W1   = (const float*)d_in[14];
    const float* b1   = (const float*)d_in[15];
    const float* W2   = (const float*)d_in[16];
    const float* b2   = (const float*)d_in[17];
    const float* Wh   = (const float*)d_in[18];
    const float* bh   = (const float*)d_in[19];
    float* out = (float*)d_out;

    char* p = (char*)d_ws;
    auto alloc = [&](size_t bytes) -> char* {
        char* r = p; p += (bytes + 255) & ~(size_t)255; return r;
    };
    float*  resid = (float*) alloc(12608ull*768*4);
    __bf16* xln   = (__bf16*)alloc(12608ull*768*2);
    __bf16* qb    = (__bf16*)alloc(768ull*197*64*2);
    __bf16* kb    = (__bf16*)alloc(768ull*197*64*2);
    __bf16* vTb   = (__bf16*)alloc(768ull*64*208*2);
    __bf16* h1    = (__bf16*)alloc(12608ull*3072*2);
    __bf16* Wpb   = (__bf16*)alloc(768ull*768*2);
    __bf16* Whb   = (__bf16*)alloc(1000ull*768*2);
    __bf16* Apat  = h1;    // alias: used only before the layer loop
    __bf16* Ahead = xln;   // alias: used only after the layer loop

    const size_t WSZ = 3072ull*768;           // elements in one W1/W2 layer slice
    size_t used = (size_t)(p - (char*)d_ws);
    bool full = ws_size >= used + 24ull*WSZ*2 + 1024;   // all-layers bf16 weights fit?
    __bf16* w1b;
    __bf16* w2b;
    if (full) {
        w1b = (__bf16*)alloc(24ull*WSZ*2);
        w2b = w1b + 12ull*WSZ;
    } else {
        w1b = (__bf16*)alloc(WSZ*2);
        w2b = (__bf16*)alloc(WSZ*2);
    }

    f2b_k<<<576, 256, 0, stream>>>(Wp, Wpb, 147456);
    f2b_k<<<750, 256, 0, stream>>>(Wh, Whb, 192000);
    if (full) {
        f2b_k<<<27648, 256, 0, stream>>>(W1, w1b, 7077888);
        f2b_k<<<27648, 256, 0, stream>>>(W2, w2b, 7077888);
    }
    pos_init_k<<<37824, 256, 0, stream>>>(cls, resid);
    vpad_k<<<2112, 256, 0, stream>>>(vTb);
    patchify_k<<<37632, 256, 0, stream>>>(x, Apat);
    gemm3_k<0><<<dim3(6, 98), 256, 0, stream>>>(Apat, Wpb, bp, resid, nullptr,
                                                12544, 768, 768, 12544, 768);
    for (int l = 0; l < 12; l++) {
        __bf16* w1l = full ? w1b + (size_t)l*WSZ : w1b;
        __bf16* w2l = full ? w2b + (size_t)l*WSZ : w2b;
        if (!full) {
            f2b_k<<<2304, 256, 0, stream>>>(W1 + (size_t)l*WSZ, w1l, 589824);
            f2b_k<<<2304, 256, 0, stream>>>(W2 + (size_t)l*WSZ, w2l, 589824);
        }
        ln_k<<<12608, 256, 0, stream>>>(resid, ln1g + l*768, ln1b + l*768, xln);
        qkv_k<<<dim3(197, 12), 256, 0, stream>>>(xln, Wq, bq, Wk, bk, Wv, bv,
                                                 qb, kb, vTb, l);
        attn_k<<<dim3(4, 12, 64), 256, 0, stream>>>(qb, kb, vTb, resid);
        ln_k<<<12608, 256, 0, stream>>>(resid, ln2g + l*768, ln2b + l*768, xln);
        gemm3_k<1><<<dim3(24, 99), 256, 0, stream>>>(xln, w1l, b1 + l*3072,
                                                     nullptr, h1,
                                                     12608, 3072, 768, 12608, 3072);
        gemm3_k<2><<<dim3(6, 99), 256, 0, stream>>>(h1, w2l, b2 + l*768,
                                                    resid, nullptr,
                                                    12608, 768, 3072, 12608, 768);
    }
    extract_k<<<192, 256, 0, stream>>>(resid, Ahead);
    gemm3_k<3><<<dim3(8, 1), 256, 0, stream>>>(Ahead, Whb, bh, out, nullptr,
                                               64, 1000, 768, 64, 1000);
}

// Round 2
// 5649.584 us; speedup vs baseline: 1.0181x; 1.0181x over previous
//
#include <hip/hip_runtime.h>

// ---------------------------------------------------------------------------
// ViT forward on MI355X (gfx950). Round 6:
//  - gemm3_k: BM=128 BN=128 BK=64, XOR-swizzled LDS (verified r5: conflicts=0),
//    NOW depth-2 software pipeline: counted s_waitcnt vmcnt(8) + raw s_barrier
//    (never drain vmcnt to 0 in the main loop) + setprio around MFMA cluster.
//  - all GEMMs (patch/MLP1/MLP2/head) via gemm3_k
// ---------------------------------------------------------------------------

typedef __bf16 v8bf __attribute__((ext_vector_type(8)));
typedef __bf16 v4bf __attribute__((ext_vector_type(4)));
typedef float  v4f  __attribute__((ext_vector_type(4)));

#define DEV static __device__ __forceinline__

DEV v8bf cvt8(float4 a, float4 b) {
    v8bf r;
    r[0]=(__bf16)a.x; r[1]=(__bf16)a.y; r[2]=(__bf16)a.z; r[3]=(__bf16)a.w;
    r[4]=(__bf16)b.x; r[5]=(__bf16)b.y; r[6]=(__bf16)b.z; r[7]=(__bf16)b.w;
    return r;
}
DEV v8bf bzero8() {
    v8bf z;
    #pragma unroll
    for (int i=0;i<8;i++) z[i]=(__bf16)0.f;
    return z;
}
DEV v4f fzero4() {
    v4f z;
    #pragma unroll
    for (int i=0;i<4;i++) z[i]=0.f;
    return z;
}
// async global->LDS, 16 bytes per lane; LDS dest = l + lane*16 (wave-uniform base)
DEV void async16(const __bf16* g, __bf16* l) {
    __builtin_amdgcn_global_load_lds(
        (const __attribute__((address_space(1))) void*)g,
        (__attribute__((address_space(3))) void*)l,
        16, 0, 0);
}

// ---------------------------------------------------------------------------
// fp32 -> bf16 elementwise (n4 = count/4)
__global__ void f2b_k(const float* __restrict__ s, __bf16* __restrict__ d, int n4) {
    int i = blockIdx.x*256 + threadIdx.x;
    if (i >= n4) return;
    float4 f = ((const float4*)s)[i];
    v4bf b;
    b[0]=(__bf16)f.x; b[1]=(__bf16)f.y; b[2]=(__bf16)f.z; b[3]=(__bf16)f.w;
    ((v4bf*)d)[i] = b;
}

// ---------------------------------------------------------------------------
// pre-fill residual with pos-embed (+cls on token 0).
__global__ void pos_init_k(const float* __restrict__ cls, float* __restrict__ resid) {
    int idx = blockIdx.x*256 + threadIdx.x;   // 9,682,944 exact
    int col = idx % 768; int rt = idx / 768;
    int ti = rt % 197;
    float v;
    if (ti == 0) v = cls[col];
    else {
        float e = (ti & 1) ? (float)(col - 1) : (float)col;
        float wj = expf(e * -0.011992630692677323f);   // ln(1e4)/768
        v = (ti & 1) ? cosf(ti*wj) : sinf(ti*wj);
    }
    resid[idx] = v;
}

// zero the vT padding (s in [197,208)) — ws is re-poisoned before each call
__global__ void vpad_k(__bf16* __restrict__ vT) {
    int idx = blockIdx.x*256 + threadIdx.x;   // 540,672 exact
    int a = idx/11, s = idx - a*11;
    vT[(size_t)a*208 + 197 + s] = (__bf16)0.f;
}

// ---------------------------------------------------------------------------
// patchify: x (64,3,224,224) fp32 -> Apat (12544,768) bf16
__global__ void patchify_k(const float* __restrict__ x, __bf16* __restrict__ Ap) {
    int idx = blockIdx.x*256 + threadIdx.x;   // 12544*768 exact
    int m = idx/768, kk = idx - m*768;
    int n = m/196, pp = m - n*196;
    int pi = pp/14, pj = pp - pi*14;
    int c = kk >> 8, rr = kk & 255, hi = rr >> 4, wi = rr & 15;
    Ap[idx] = (__bf16)x[((size_t)((n*3 + c)*224 + pi*16 + hi))*224 + pj*16 + wi];
}

// extract: residual token-0 rows -> Ahead (64,768) bf16
__global__ void extract_k(const float* __restrict__ resid, __bf16* __restrict__ Ah) {
    int idx = blockIdx.x*256 + threadIdx.x;   // 49152 exact
    int n = idx/768, d = idx - n*768;
    Ah[idx] = (__bf16)resid[(size_t)(n*197)*768 + d];
}

// ---------------------------------------------------------------------------
// LayerNorm over D=768: fp32 in -> bf16 out. One block per row.
__global__ __launch_bounds__(256) void ln_k(const float* __restrict__ resid,
                                            const float* __restrict__ gamma,
                                            const float* __restrict__ beta,
                                            __bf16* __restrict__ out) {
    __shared__ float red[4];
    int row = blockIdx.x, t = threadIdx.x;
    const float* xr = resid + (size_t)row*768;
    float x0 = xr[t], x1 = xr[t+256], x2 = xr[t+512];
    float s = x0+x1+x2;
    #pragma unroll
    for (int off=1; off<64; off<<=1) s += __shfl_xor(s, off, 64);
    if ((t&63)==0) red[t>>6] = s;
    __syncthreads();
    float mu = (red[0]+red[1]+red[2]+red[3]) * (1.f/768.f);
    __syncthreads();
    float d0=x0-mu, d1=x1-mu, d2=x2-mu;
    float q = d0*d0 + d1*d1 + d2*d2;
    #pragma unroll
    for (int off=1; off<64; off<<=1) q += __shfl_xor(q, off, 64);
    if ((t&63)==0) red[t>>6] = q;
    __syncthreads();
    float var = (red[0]+red[1]+red[2]+red[3]) * (1.f/768.f);
    float rs = rsqrtf(var + 1e-5f);
    __bf16* o = out + (size_t)row*768;
    o[t]     = (__bf16)(d0*rs*gamma[t]     + beta[t]);
    o[t+256] = (__bf16)(d1*rs*gamma[t+256] + beta[t+256]);
    o[t+512] = (__bf16)(d2*rs*gamma[t+512] + beta[t+512]);
}

// ---------------------------------------------------------------------------
// GEMM: C[m][n] = sum_k A[m][k]*B[n][k], A,B bf16. Tile 128x128x64.
// Depth-2 pipeline: two LDS buffers, stage tile t+2 after finishing compute of
// tile t; before computing tile t wait vmcnt(8) (only the YOUNGER stage stays
// in flight) + s_barrier. vmcnt never drains to 0 mid-loop (T4).
// Each wave issues exactly 8 global_load_lds per stage -> counts are exact.
// XOR swizzle: physical 16B slot p of row r holds logical slot p^(r&7);
// source pre-swizzled (global_load_lds writes linearly), reads apply same XOR.
// EPI: 0 = +bias, patch-embed row remap (n*197+p+1), += into resid
//      1 = +bias, GELU -> bf16
//      2 = +bias, += resid fp32
//      3 = +bias -> fp32 out
template<int EPI>
__global__ __launch_bounds__(256) void gemm3_k(
    const __bf16* __restrict__ A, const __bf16* __restrict__ B,
    const float* __restrict__ bias,
    float* __restrict__ outf, __bf16* __restrict__ outb,
    int M, int N, int K, int MV, int NV)
{
    __shared__ __align__(16) __bf16 As[2][128*64];
    __shared__ __align__(16) __bf16 Bs[2][128*64];
    const int tid = threadIdx.x, lane = tid & 63, w = tid >> 6;
    const int m0 = blockIdx.y * 128, n0 = blockIdx.x * 128;
    const int rw = (w & 1) * 64, cw = (w >> 1) * 64;
    const int lg = lane >> 4, lc = lane & 15;
    const int lr = lane >> 3;
    const int lk8s = (((lane & 7) ^ lr) * 8);  // pre-swizzled source 16B slot

    v4f acc[4][4];
    #pragma unroll
    for (int i=0;i<4;i++)
        #pragma unroll
        for (int j=0;j<4;j++) acc[i][j] = fzero4();

    const int NK = K >> 6;
    // stage: A 16 chunks (4/wave), B 16 chunks (4/wave); chunk = 8 rows of 64.
    // 8 global_load_lds per wave per call (vmcnt accounting relies on this).
    auto stage = [&](int buf, int kt) {
        #pragma unroll
        for (int i=0;i<4;i++) {
            int chunk = w*4 + i;
            int r = chunk*8 + lr;
            int gr = m0 + r; gr = gr < M ? gr : M-1;
            async16(A + (size_t)gr*K + kt + lk8s, &As[buf][chunk*512]);
        }
        #pragma unroll
        for (int i=0;i<4;i++) {
            int chunk = w*4 + i;
            int r = chunk*8 + lr;
            int gc = n0 + r; gc = gc < N ? gc : N-1;
            async16(B + (size_t)gc*K + kt + lk8s, &Bs[buf][chunk*512]);
        }
    };

    stage(0, 0);
    if (NK > 1) stage(1, 64);
    for (int ki = 0; ki < NK; ki++) {
        // Wait for buf[ki&1]'s loads: if a younger stage is in flight, leave
        // its 8 loads outstanding; at the final tile drain fully.
        if (ki + 1 < NK) asm volatile("s_waitcnt vmcnt(8)" ::: "memory");
        else             asm volatile("s_waitcnt vmcnt(0)" ::: "memory");
        __builtin_amdgcn_s_barrier();
        __builtin_amdgcn_sched_barrier(0);   // keep ds_reads below the barrier

        const __bf16* as = As[ki & 1];
        const __bf16* bs = Bs[ki & 1];
        #pragma unroll
        for (int ks=0; ks<2; ks++) {
            v8bf af[4], bf[4];
            #pragma unroll
            for (int i=0;i<4;i++) {
                int row = rw + i*16 + lc;
                af[i] = *(const v8bf*)&as[row*64 + (((ks*4 + lg) ^ (row & 7)) << 3)];
            }
            #pragma unroll
            for (int j=0;j<4;j++) {
                int row = cw + j*16 + lc;
                bf[j] = *(const v8bf*)&bs[row*64 + (((ks*4 + lg) ^ (row & 7)) << 3)];
            }
            __builtin_amdgcn_s_setprio(1);
            #pragma unroll
            for (int i=0;i<4;i++)
                #pragma unroll
                for (int j=0;j<4;j++)
                    acc[i][j] = __builtin_amdgcn_mfma_f32_16x16x32_bf16(
                        af[i], bf[j], acc[i][j], 0, 0, 0);
            __builtin_amdgcn_s_setprio(0);
        }

        __builtin_amdgcn_sched_barrier(0);   // keep ds_reads above the barrier
        __builtin_amdgcn_s_barrier();        // all waves done reading buf[ki&1]
        __builtin_amdgcn_sched_barrier(0);   // keep stage below the barrier
        if (ki + 2 < NK) stage(ki & 1, (ki + 2) << 6);
    }

    #pragma unroll
    for (int i=0;i<4;i++)
        #pragma unroll
        for (int j=0;j<4;j++)
            #pragma unroll
            for (int r=0;r<4;r++) {
                int row = m0 + rw + i*16 + lg*4 + r;
                int col = n0 + cw + j*16 + lc;
                if (row >= MV || col >= NV) continue;
                float v = acc[i][j][r];
                if constexpr (EPI == 0) {
                    int n = row / 196, p = row - n*196;
                    outf[((size_t)(n*197 + p + 1))*768 + col] += v + bias[col];
                } else if constexpr (EPI == 1) {
                    float tt = v + bias[col];
                    outb[(size_t)row*NV + col] =
                        (__bf16)(0.5f*tt*(1.f + erff(tt*0.70710678118654752f)));
                } else if constexpr (EPI == 2) {
                    outf[(size_t)row*NV + col] += v + bias[col];
                } else {
                    outf[(size_t)row*NV + col] = v + bias[col];
                }
            }
}

// ---------------------------------------------------------------------------
// Per-head QKV projection. Grid (197 m-tiles of 64, 12 heads).
__global__ __launch_bounds__(256) void qkv_k(
    const __bf16* __restrict__ xln,
    const float* __restrict__ Wq, const float* __restrict__ bq,
    const float* __restrict__ Wk, const float* __restrict__ bk,
    const float* __restrict__ Wv, const float* __restrict__ bv,
    __bf16* __restrict__ qo, __bf16* __restrict__ ko, __bf16* __restrict__ vT,
    int l)
{
    constexpr int LDT = 72;
    __shared__ __align__(16) __bf16 Xs[64*LDT];
    __shared__ __align__(16) __bf16 Ws[3*64*LDT];
    const int tid = threadIdx.x, lane = tid & 63, w = tid >> 6;
    const int lg = lane >> 4, lc = lane & 15;
    const int m0 = blockIdx.x * 64, h = blockIdx.y;
    const int off = (l*12 + h) * 4096, bo = (l*12 + h) * 64;
    const float* Wm[3] = {Wq + off, Wk + off, Wv + off};
    const float* Bm[3] = {bq + bo, bk + bo, bv + bo};

    #pragma unroll
    for (int i=0;i<2;i++) {
        int c = i*256 + tid, r = c >> 3, k8 = (c & 7) * 8;
        *(v8bf*)&Xs[r*LDT + k8] = *(const v8bf*)(xln + (size_t)(m0+r)*768 + h*64 + k8);
    }
    #pragma unroll
    for (int mat=0; mat<3; mat++)
        #pragma unroll
        for (int i=0;i<2;i++) {
            int c = i*256 + tid, r = c >> 3, k8 = (c & 7) * 8;
            const float* p = Wm[mat] + r*64 + k8;
            *(v8bf*)&Ws[mat*64*LDT + r*LDT + k8] =
                cvt8(*(const float4*)p, *(const float4*)(p+4));
        }
    __syncthreads();

    v8bf af[2];
    af[0] = *(const v8bf*)&Xs[(w*16 + lc)*LDT + lg*8];
    af[1] = *(const v8bf*)&Xs[(w*16 + lc)*LDT + 32 + lg*8];
    v4f acc[3][4];
    #pragma unroll
    for (int m=0;m<3;m++)
        #pragma unroll
        for (int j=0;j<4;j++) acc[m][j] = fzero4();

    #pragma unroll
    for (int mat=0; mat<3; mat++)
        #pragma unroll
        for (int ks=0; ks<2; ks++)
            #pragma unroll
            for (int nt=0; nt<4; nt++) {
                v8bf bf = *(const v8bf*)&Ws[mat*64*LDT + (nt*16 + lc)*LDT + ks*32 + lg*8];
                acc[mat][nt] = __builtin_amdgcn_mfma_f32_16x16x32_bf16(
                    af[ks], bf, acc[mat][nt], 0, 0, 0);
            }

    #pragma unroll
    for (int mat=0; mat<3; mat++)
        #pragma unroll
        for (int nt=0; nt<4; nt++)
            #pragma unroll
            for (int r=0; r<4; r++) {
                int row = m0 + w*16 + lg*4 + r;
                int n = row / 197, s = row - n*197;
                int o = nt*16 + lc;
                float v = acc[mat][nt][r] + Bm[mat][o];
                if (mat == 0)
                    qo[(size_t)((n*12 + h)*197 + s)*64 + o] = (__bf16)v;
                else if (mat == 1)
                    ko[(size_t)((n*12 + h)*197 + s)*64 + o] = (__bf16)v;
                else
                    vT[(size_t)((n*12 + h)*64 + o)*208 + s] = (__bf16)v;
            }
}

// ---------------------------------------------------------------------------
// Attention for one (n,h,qtile-of-64). S=197 padded to 224 keys.
__global__ __launch_bounds__(256) void attn_k(
    const __bf16* __restrict__ q, const __bf16* __restrict__ k,
    const __bf16* __restrict__ vT, float* __restrict__ resid)
{
    __shared__ __align__(16) __bf16 KP[224*72];    // K tile, later aliased as P
    __shared__ __align__(16) __bf16 Vsh[64*232];   // V^T tile [dh][key]
    const int tid = threadIdx.x, lane = tid & 63, w = tid >> 6;
    const int lg = lane >> 4, lc = lane & 15;
    const int q0 = blockIdx.x * 64, h = blockIdx.y, n = blockIdx.z;
    const size_t nh = n*12 + h;
    const __bf16* kg = k  + nh*197*64;
    const __bf16* vg = vT + nh*64*208;
    const __bf16* qg = q  + nh*197*64;
    const v8bf z8 = bzero8();

    #pragma unroll
    for (int i=0;i<7;i++) {
        int c = i*256 + tid, r = c >> 3, k8 = (c & 7) * 8;
        v8bf val = (r < 197) ? *(const v8bf*)(kg + r*64 + k8) : z8;
        *(v8bf*)&KP[r*72 + k8] = val;
    }
    #pragma unroll
    for (int i=0;i<7;i++) {
        int c = i*256 + tid, r = c/28, s8 = (c - r*28) * 8;
        v8bf val = (s8 < 208) ? *(const v8bf*)(vg + r*208 + s8) : z8;
        *(v8bf*)&Vsh[r*232 + s8] = val;
    }
    int qs = q0 + w*16 + lc; qs = qs < 197 ? qs : 196;
    v8bf aq0 = *(const v8bf*)(qg + qs*64 + lg*8);
    v8bf aq1 = *(const v8bf*)(qg + qs*64 + 32 + lg*8);
    __syncthreads();

    v4f sc[14];
    #pragma unroll
    for (int nt=0; nt<14; nt++) sc[nt] = fzero4();
    #pragma unroll
    for (int nt=0; nt<14; nt++) {
        v8bf b0 = *(const v8bf*)&KP[(nt*16 + lc)*72 + lg*8];
        v8bf b1 = *(const v8bf*)&KP[(nt*16 + lc)*72 + 32 + lg*8];
        sc[nt] = __builtin_amdgcn_mfma_f32_16x16x32_bf16(aq0, b0, sc[nt], 0,0,0);
        sc[nt] = __builtin_amdgcn_mfma_f32_16x16x32_bf16(aq1, b1, sc[nt], 0,0,0);
    }
    __syncthreads();

    #pragma unroll
    for (int r=0; r<4; r++) {
        float mx = -1e30f;
        #pragma unroll
        for (int nt=0; nt<14; nt++)
            if (nt*16 + lc < 197) mx = fmaxf(mx, sc[nt][r]);
        #pragma unroll
        for (int off=1; off<16; off<<=1) mx = fmaxf(mx, __shfl_xor(mx, off, 64));
        float sm = 0.f;
        #pragma unroll
        for (int nt=0; nt<14; nt++) {
            float p = (nt*16 + lc < 197) ? expf((sc[nt][r] - mx) * 0.125f) : 0.f;
            sc[nt][r] = p; sm += p;
        }
        #pragma unroll
        for (int off=1; off<16; off<<=1) sm += __shfl_xor(sm, off, 64);
        float inv = 1.f / sm;
        int prow = w*16 + lg*4 + r;
        #pragma unroll
        for (int nt=0; nt<14; nt++)
            KP[prow*232 + nt*16 + lc] = (__bf16)(sc[nt][r] * inv);
    }

    v4f ov[4];
    #pragma unroll
    for (int nt=0; nt<4; nt++) ov[nt] = fzero4();
    #pragma unroll
    for (int ks=0; ks<7; ks++) {
        v8bf a = *(const v8bf*)&KP[(w*16 + lc)*232 + ks*32 + lg*8];
        #pragma unroll
        for (int nt=0; nt<4; nt++) {
            v8bf b = *(const v8bf*)&Vsh[(nt*16 + lc)*232 + ks*32 + lg*8];
            ov[nt] = __builtin_amdgcn_mfma_f32_16x16x32_bf16(a, b, ov[nt], 0,0,0);
        }
    }
    #pragma unroll
    for (int nt=0; nt<4; nt++)
        #pragma unroll
        for (int r=0; r<4; r++) {
            int qrow = q0 + w*16 + lg*4 + r;
            if (qrow < 197) {
                float* p = resid + ((size_t)n*197 + qrow)*768 + h*64 + nt*16 + lc;
                *p += ov[nt][r];
            }
        }
}

// ---------------------------------------------------------------------------
extern "C" void kernel_launch(void* const* d_in, const int* in_sizes, int n_in,
                              void* d_out, int out_size, void* d_ws, size_t ws_size,
                              hipStream_t stream) {
    const float* x    = (const float*)d_in[0];
    const float* Wp   = (const float*)d_in[1];
    const float* bp   = (const float*)d_in[2];
    const float* cls  = (const float*)d_in[3];
    const float* ln1g = (const float*)d_in[4];
    const float* ln1b = (const float*)d_in[5];
    const float* Wq   = (const float*)d_in[6];
    const float* bq   = (const float*)d_in[7];
    const float* Wk   = (const float*)d_in[8];
    const float* bk   = (const float*)d_in[9];
    const float* Wv   = (const float*)d_in[10];
    const float* bv   = (const float*)d_in[11];
    const float* ln2g = (const float*)d_in[12];
    const float* ln2b = (const float*)d_in[13];
    const float* W1   = (const float*)d_in[14];
    const float* b1   = (const float*)d_in[15];
    const float* W2   = (const float*)d_in[16];
    const float* b2   = (const float*)d_in[17];
    const float* Wh   = (const float*)d_in[18];
    const float* bh   = (const float*)d_in[19];
    float* out = (float*)d_out;

    char* p = (char*)d_ws;
    auto alloc = [&](size_t bytes) -> char* {
        char* r = p; p += (bytes + 255) & ~(size_t)255; return r;
    };
    float*  resid = (float*) alloc(12608ull*768*4);
    __bf16* xln   = (__bf16*)alloc(12608ull*768*2);
    __bf16* qb    = (__bf16*)alloc(768ull*197*64*2);
    __bf16* kb    = (__bf16*)alloc(768ull*197*64*2);
    __bf16* vTb   = (__bf16*)alloc(768ull*64*208*2);
    __bf16* h1    = (__bf16*)alloc(12608ull*3072*2);
    __bf16* Wpb   = (__bf16*)alloc(768ull*768*2);
    __bf16* Whb   = (__bf16*)alloc(1000ull*768*2);
    __bf16* Apat  = h1;    // alias: used only before the layer loop
    __bf16* Ahead = xln;   // alias: used only after the layer loop

    const size_t WSZ = 3072ull*768;           // elements in one W1/W2 layer slice
    size_t used = (size_t)(p - (char*)d_ws);
    bool full = ws_size >= used + 24ull*WSZ*2 + 1024;   // all-layers bf16 weights fit?
    __bf16* w1b;
    __bf16* w2b;
    if (full) {
        w1b = (__bf16*)alloc(24ull*WSZ*2);
        w2b = w1b + 12ull*WSZ;
    } else {
        w1b = (__bf16*)alloc(WSZ*2);
        w2b = (__bf16*)alloc(WSZ*2);
    }

    f2b_k<<<576, 256, 0, stream>>>(Wp, Wpb, 147456);
    f2b_k<<<750, 256, 0, stream>>>(Wh, Whb, 192000);
    if (full) {
        f2b_k<<<27648, 256, 0, stream>>>(W1, w1b, 7077888);
        f2b_k<<<27648, 256, 0, stream>>>(W2, w2b, 7077888);
    }
    pos_init_k<<<37824, 256, 0, stream>>>(cls, resid);
    vpad_k<<<2112, 256, 0, stream>>>(vTb);
    patchify_k<<<37632, 256, 0, stream>>>(x, Apat);
    gemm3_k<0><<<dim3(6, 98), 256, 0, stream>>>(Apat, Wpb, bp, resid, nullptr,
                                                12544, 768, 768, 12544, 768);
    for (int l = 0; l < 12; l++) {
        __bf16* w1l = full ? w1b + (size_t)l*WSZ : w1b;
        __bf16* w2l = full ? w2b + (size_t)l*WSZ : w2b;
        if (!full) {
            f2b_k<<<2304, 256, 0, stream>>>(W1 + (size_t)l*WSZ, w1l, 589824);
            f2b_k<<<2304, 256, 0, stream>>>(W2 + (size_t)l*WSZ, w2l, 589824);
        }
        ln_k<<<12608, 256, 0, stream>>>(resid, ln1g + l*768, ln1b + l*768, xln);
        qkv_k<<<dim3(197, 12), 256, 0, stream>>>(xln, Wq, bq, Wk, bk, Wv, bv,
                                                 qb, kb, vTb, l);
        attn_k<<<dim3(4, 12, 64), 256, 0, stream>>>(qb, kb, vTb, resid);
        ln_k<<<12608, 256, 0, stream>>>(resid, ln2g + l*768, ln2b + l*768, xln);
        gemm3_k<1><<<dim3(24, 99), 256, 0, stream>>>(xln, w1l, b1 + l*3072,
                                                     nullptr, h1,
                                                     12608, 3072, 768, 12608, 3072);
        gemm3_k<2><<<dim3(6, 99), 256, 0, stream>>>(h1, w2l, b2 + l*768,
                                                    resid, nullptr,
                                                    12608, 768, 3072, 12608, 768);
    }
    extract_k<<<192, 256, 0, stream>>>(resid, Ahead);
    gemm3_k<3><<<dim3(8, 1), 256, 0, stream>>>(Ahead, Whb, bh, out, nullptr,
                                               64, 1000, 768, 64, 1000);
}

// Round 3
// 4910.333 us; speedup vs baseline: 1.1714x; 1.1506x over previous
//
#include <hip/hip_runtime.h>

// ---------------------------------------------------------------------------
// ViT forward on MI355X (gfx950). Round 7:
//  - gemm3_k: BM=128 BN=128 BK=64, SINGLE-buffer LDS (32KB -> 5 blocks/CU,
//    m97-proven structure: stage -> sync -> compute -> sync). XOR-swizzled
//    LDS (r5-verified: conflicts=0). No inline vmcnt / setprio (m190/m99).
//    Cross-block TLP (5 blocks/CU) hides staging latency, not intra-block dbuf.
//  - all GEMMs (patch/MLP1/MLP2/head) via gemm3_k
// ---------------------------------------------------------------------------

typedef __bf16 v8bf __attribute__((ext_vector_type(8)));
typedef __bf16 v4bf __attribute__((ext_vector_type(4)));
typedef float  v4f  __attribute__((ext_vector_type(4)));

#define DEV static __device__ __forceinline__

DEV v8bf cvt8(float4 a, float4 b) {
    v8bf r;
    r[0]=(__bf16)a.x; r[1]=(__bf16)a.y; r[2]=(__bf16)a.z; r[3]=(__bf16)a.w;
    r[4]=(__bf16)b.x; r[5]=(__bf16)b.y; r[6]=(__bf16)b.z; r[7]=(__bf16)b.w;
    return r;
}
DEV v8bf bzero8() {
    v8bf z;
    #pragma unroll
    for (int i=0;i<8;i++) z[i]=(__bf16)0.f;
    return z;
}
DEV v4f fzero4() {
    v4f z;
    #pragma unroll
    for (int i=0;i<4;i++) z[i]=0.f;
    return z;
}
// async global->LDS, 16 bytes per lane; LDS dest = l + lane*16 (wave-uniform base)
DEV void async16(const __bf16* g, __bf16* l) {
    __builtin_amdgcn_global_load_lds(
        (const __attribute__((address_space(1))) void*)g,
        (__attribute__((address_space(3))) void*)l,
        16, 0, 0);
}

// ---------------------------------------------------------------------------
// fp32 -> bf16 elementwise (n4 = count/4)
__global__ void f2b_k(const float* __restrict__ s, __bf16* __restrict__ d, int n4) {
    int i = blockIdx.x*256 + threadIdx.x;
    if (i >= n4) return;
    float4 f = ((const float4*)s)[i];
    v4bf b;
    b[0]=(__bf16)f.x; b[1]=(__bf16)f.y; b[2]=(__bf16)f.z; b[3]=(__bf16)f.w;
    ((v4bf*)d)[i] = b;
}

// ---------------------------------------------------------------------------
// pre-fill residual with pos-embed (+cls on token 0).
__global__ void pos_init_k(const float* __restrict__ cls, float* __restrict__ resid) {
    int idx = blockIdx.x*256 + threadIdx.x;   // 9,682,944 exact
    int col = idx % 768; int rt = idx / 768;
    int ti = rt % 197;
    float v;
    if (ti == 0) v = cls[col];
    else {
        float e = (ti & 1) ? (float)(col - 1) : (float)col;
        float wj = expf(e * -0.011992630692677323f);   // ln(1e4)/768
        v = (ti & 1) ? cosf(ti*wj) : sinf(ti*wj);
    }
    resid[idx] = v;
}

// zero the vT padding (s in [197,208)) — ws is re-poisoned before each call
__global__ void vpad_k(__bf16* __restrict__ vT) {
    int idx = blockIdx.x*256 + threadIdx.x;   // 540,672 exact
    int a = idx/11, s = idx - a*11;
    vT[(size_t)a*208 + 197 + s] = (__bf16)0.f;
}

// ---------------------------------------------------------------------------
// patchify: x (64,3,224,224) fp32 -> Apat (12544,768) bf16
__global__ void patchify_k(const float* __restrict__ x, __bf16* __restrict__ Ap) {
    int idx = blockIdx.x*256 + threadIdx.x;   // 12544*768 exact
    int m = idx/768, kk = idx - m*768;
    int n = m/196, pp = m - n*196;
    int pi = pp/14, pj = pp - pi*14;
    int c = kk >> 8, rr = kk & 255, hi = rr >> 4, wi = rr & 15;
    Ap[idx] = (__bf16)x[((size_t)((n*3 + c)*224 + pi*16 + hi))*224 + pj*16 + wi];
}

// extract: residual token-0 rows -> Ahead (64,768) bf16
__global__ void extract_k(const float* __restrict__ resid, __bf16* __restrict__ Ah) {
    int idx = blockIdx.x*256 + threadIdx.x;   // 49152 exact
    int n = idx/768, d = idx - n*768;
    Ah[idx] = (__bf16)resid[(size_t)(n*197)*768 + d];
}

// ---------------------------------------------------------------------------
// LayerNorm over D=768: fp32 in -> bf16 out. One block per row.
__global__ __launch_bounds__(256) void ln_k(const float* __restrict__ resid,
                                            const float* __restrict__ gamma,
                                            const float* __restrict__ beta,
                                            __bf16* __restrict__ out) {
    __shared__ float red[4];
    int row = blockIdx.x, t = threadIdx.x;
    const float* xr = resid + (size_t)row*768;
    float x0 = xr[t], x1 = xr[t+256], x2 = xr[t+512];
    float s = x0+x1+x2;
    #pragma unroll
    for (int off=1; off<64; off<<=1) s += __shfl_xor(s, off, 64);
    if ((t&63)==0) red[t>>6] = s;
    __syncthreads();
    float mu = (red[0]+red[1]+red[2]+red[3]) * (1.f/768.f);
    __syncthreads();
    float d0=x0-mu, d1=x1-mu, d2=x2-mu;
    float q = d0*d0 + d1*d1 + d2*d2;
    #pragma unroll
    for (int off=1; off<64; off<<=1) q += __shfl_xor(q, off, 64);
    if ((t&63)==0) red[t>>6] = q;
    __syncthreads();
    float var = (red[0]+red[1]+red[2]+red[3]) * (1.f/768.f);
    float rs = rsqrtf(var + 1e-5f);
    __bf16* o = out + (size_t)row*768;
    o[t]     = (__bf16)(d0*rs*gamma[t]     + beta[t]);
    o[t+256] = (__bf16)(d1*rs*gamma[t+256] + beta[t+256]);
    o[t+512] = (__bf16)(d2*rs*gamma[t+512] + beta[t+512]);
}

// ---------------------------------------------------------------------------
// GEMM: C[m][n] = sum_k A[m][k]*B[n][k], A,B bf16. Tile 128x128x64.
// Single-buffer LDS (32KB -> 5 blocks/CU): per K-iter stage -> syncthreads
// (drains vmcnt) -> compute -> syncthreads. Latency hidden by 5 resident
// blocks per CU (m97/m114 pattern), not intra-block pipelining.
// XOR swizzle: physical 16B slot p of row r holds logical slot p^(r&7);
// source pre-swizzled (global_load_lds writes linearly), reads apply same XOR.
// EPI: 0 = +bias, patch-embed row remap (n*197+p+1), += into resid
//      1 = +bias, GELU -> bf16
//      2 = +bias, += resid fp32
//      3 = +bias -> fp32 out
template<int EPI>
__global__ __launch_bounds__(256) void gemm3_k(
    const __bf16* __restrict__ A, const __bf16* __restrict__ B,
    const float* __restrict__ bias,
    float* __restrict__ outf, __bf16* __restrict__ outb,
    int M, int N, int K, int MV, int NV)
{
    __shared__ __align__(16) __bf16 As[128*64];
    __shared__ __align__(16) __bf16 Bs[128*64];
    const int tid = threadIdx.x, lane = tid & 63, w = tid >> 6;
    const int m0 = blockIdx.y * 128, n0 = blockIdx.x * 128;
    const int rw = (w & 1) * 64, cw = (w >> 1) * 64;
    const int lg = lane >> 4, lc = lane & 15;
    const int lr = lane >> 3;
    const int lk8s = (((lane & 7) ^ lr) * 8);  // pre-swizzled source 16B slot

    v4f acc[4][4];
    #pragma unroll
    for (int i=0;i<4;i++)
        #pragma unroll
        for (int j=0;j<4;j++) acc[i][j] = fzero4();

    const int NK = K >> 6;
    // stage: A 16 chunks (4/wave), B 16 chunks (4/wave); chunk = 8 rows of 64.
    auto stage = [&](int kt) {
        #pragma unroll
        for (int i=0;i<4;i++) {
            int chunk = w*4 + i;
            int r = chunk*8 + lr;
            int gr = m0 + r; gr = gr < M ? gr : M-1;
            async16(A + (size_t)gr*K + kt + lk8s, &As[chunk*512]);
        }
        #pragma unroll
        for (int i=0;i<4;i++) {
            int chunk = w*4 + i;
            int r = chunk*8 + lr;
            int gc = n0 + r; gc = gc < N ? gc : N-1;
            async16(B + (size_t)gc*K + kt + lk8s, &Bs[chunk*512]);
        }
    };

    for (int ki = 0; ki < NK; ki++) {
        stage(ki << 6);
        __syncthreads();              // drains vmcnt+lgkm: tile ready
        #pragma unroll
        for (int ks=0; ks<2; ks++) {
            v8bf af[4], bf[4];
            #pragma unroll
            for (int i=0;i<4;i++) {
                int row = rw + i*16 + lc;
                af[i] = *(const v8bf*)&As[row*64 + (((ks*4 + lg) ^ (row & 7)) << 3)];
            }
            #pragma unroll
            for (int j=0;j<4;j++) {
                int row = cw + j*16 + lc;
                bf[j] = *(const v8bf*)&Bs[row*64 + (((ks*4 + lg) ^ (row & 7)) << 3)];
            }
            #pragma unroll
            for (int i=0;i<4;i++)
                #pragma unroll
                for (int j=0;j<4;j++)
                    acc[i][j] = __builtin_amdgcn_mfma_f32_16x16x32_bf16(
                        af[i], bf[j], acc[i][j], 0, 0, 0);
        }
        __syncthreads();              // all waves done reading before restage
    }

    #pragma unroll
    for (int i=0;i<4;i++)
        #pragma unroll
        for (int j=0;j<4;j++)
            #pragma unroll
            for (int r=0;r<4;r++) {
                int row = m0 + rw + i*16 + lg*4 + r;
                int col = n0 + cw + j*16 + lc;
                if (row >= MV || col >= NV) continue;
                float v = acc[i][j][r];
                if constexpr (EPI == 0) {
                    int n = row / 196, p = row - n*196;
                    outf[((size_t)(n*197 + p + 1))*768 + col] += v + bias[col];
                } else if constexpr (EPI == 1) {
                    float tt = v + bias[col];
                    outb[(size_t)row*NV + col] =
                        (__bf16)(0.5f*tt*(1.f + erff(tt*0.70710678118654752f)));
                } else if constexpr (EPI == 2) {
                    outf[(size_t)row*NV + col] += v + bias[col];
                } else {
                    outf[(size_t)row*NV + col] = v + bias[col];
                }
            }
}

// ---------------------------------------------------------------------------
// Per-head QKV projection. Grid (197 m-tiles of 64, 12 heads).
__global__ __launch_bounds__(256) void qkv_k(
    const __bf16* __restrict__ xln,
    const float* __restrict__ Wq, const float* __restrict__ bq,
    const float* __restrict__ Wk, const float* __restrict__ bk,
    const float* __restrict__ Wv, const float* __restrict__ bv,
    __bf16* __restrict__ qo, __bf16* __restrict__ ko, __bf16* __restrict__ vT,
    int l)
{
    constexpr int LDT = 72;
    __shared__ __align__(16) __bf16 Xs[64*LDT];
    __shared__ __align__(16) __bf16 Ws[3*64*LDT];
    const int tid = threadIdx.x, lane = tid & 63, w = tid >> 6;
    const int lg = lane >> 4, lc = lane & 15;
    const int m0 = blockIdx.x * 64, h = blockIdx.y;
    const int off = (l*12 + h) * 4096, bo = (l*12 + h) * 64;
    const float* Wm[3] = {Wq + off, Wk + off, Wv + off};
    const float* Bm[3] = {bq + bo, bk + bo, bv + bo};

    #pragma unroll
    for (int i=0;i<2;i++) {
        int c = i*256 + tid, r = c >> 3, k8 = (c & 7) * 8;
        *(v8bf*)&Xs[r*LDT + k8] = *(const v8bf*)(xln + (size_t)(m0+r)*768 + h*64 + k8);
    }
    #pragma unroll
    for (int mat=0; mat<3; mat++)
        #pragma unroll
        for (int i=0;i<2;i++) {
            int c = i*256 + tid, r = c >> 3, k8 = (c & 7) * 8;
            const float* p = Wm[mat] + r*64 + k8;
            *(v8bf*)&Ws[mat*64*LDT + r*LDT + k8] =
                cvt8(*(const float4*)p, *(const float4*)(p+4));
        }
    __syncthreads();

    v8bf af[2];
    af[0] = *(const v8bf*)&Xs[(w*16 + lc)*LDT + lg*8];
    af[1] = *(const v8bf*)&Xs[(w*16 + lc)*LDT + 32 + lg*8];
    v4f acc[3][4];
    #pragma unroll
    for (int m=0;m<3;m++)
        #pragma unroll
        for (int j=0;j<4;j++) acc[m][j] = fzero4();

    #pragma unroll
    for (int mat=0; mat<3; mat++)
        #pragma unroll
        for (int ks=0; ks<2; ks++)
            #pragma unroll
            for (int nt=0; nt<4; nt++) {
                v8bf bf = *(const v8bf*)&Ws[mat*64*LDT + (nt*16 + lc)*LDT + ks*32 + lg*8];
                acc[mat][nt] = __builtin_amdgcn_mfma_f32_16x16x32_bf16(
                    af[ks], bf, acc[mat][nt], 0, 0, 0);
            }

    #pragma unroll
    for (int mat=0; mat<3; mat++)
        #pragma unroll
        for (int nt=0; nt<4; nt++)
            #pragma unroll
            for (int r=0; r<4; r++) {
                int row = m0 + w*16 + lg*4 + r;
                int n = row / 197, s = row - n*197;
                int o = nt*16 + lc;
                float v = acc[mat][nt][r] + Bm[mat][o];
                if (mat == 0)
                    qo[(size_t)((n*12 + h)*197 + s)*64 + o] = (__bf16)v;
                else if (mat == 1)
                    ko[(size_t)((n*12 + h)*197 + s)*64 + o] = (__bf16)v;
                else
                    vT[(size_t)((n*12 + h)*64 + o)*208 + s] = (__bf16)v;
            }
}

// ---------------------------------------------------------------------------
// Attention for one (n,h,qtile-of-64). S=197 padded to 224 keys.
__global__ __launch_bounds__(256) void attn_k(
    const __bf16* __restrict__ q, const __bf16* __restrict__ k,
    const __bf16* __restrict__ vT, float* __restrict__ resid)
{
    __shared__ __align__(16) __bf16 KP[224*72];    // K tile, later aliased as P
    __shared__ __align__(16) __bf16 Vsh[64*232];   // V^T tile [dh][key]
    const int tid = threadIdx.x, lane = tid & 63, w = tid >> 6;
    const int lg = lane >> 4, lc = lane & 15;
    const int q0 = blockIdx.x * 64, h = blockIdx.y, n = blockIdx.z;
    const size_t nh = n*12 + h;
    const __bf16* kg = k  + nh*197*64;
    const __bf16* vg = vT + nh*64*208;
    const __bf16* qg = q  + nh*197*64;
    const v8bf z8 = bzero8();

    #pragma unroll
    for (int i=0;i<7;i++) {
        int c = i*256 + tid, r = c >> 3, k8 = (c & 7) * 8;
        v8bf val = (r < 197) ? *(const v8bf*)(kg + r*64 + k8) : z8;
        *(v8bf*)&KP[r*72 + k8] = val;
    }
    #pragma unroll
    for (int i=0;i<7;i++) {
        int c = i*256 + tid, r = c/28, s8 = (c - r*28) * 8;
        v8bf val = (s8 < 208) ? *(const v8bf*)(vg + r*208 + s8) : z8;
        *(v8bf*)&Vsh[r*232 + s8] = val;
    }
    int qs = q0 + w*16 + lc; qs = qs < 197 ? qs : 196;
    v8bf aq0 = *(const v8bf*)(qg + qs*64 + lg*8);
    v8bf aq1 = *(const v8bf*)(qg + qs*64 + 32 + lg*8);
    __syncthreads();

    v4f sc[14];
    #pragma unroll
    for (int nt=0; nt<14; nt++) sc[nt] = fzero4();
    #pragma unroll
    for (int nt=0; nt<14; nt++) {
        v8bf b0 = *(const v8bf*)&KP[(nt*16 + lc)*72 + lg*8];
        v8bf b1 = *(const v8bf*)&KP[(nt*16 + lc)*72 + 32 + lg*8];
        sc[nt] = __builtin_amdgcn_mfma_f32_16x16x32_bf16(aq0, b0, sc[nt], 0,0,0);
        sc[nt] = __builtin_amdgcn_mfma_f32_16x16x32_bf16(aq1, b1, sc[nt], 0,0,0);
    }
    __syncthreads();

    #pragma unroll
    for (int r=0; r<4; r++) {
        float mx = -1e30f;
        #pragma unroll
        for (int nt=0; nt<14; nt++)
            if (nt*16 + lc < 197) mx = fmaxf(mx, sc[nt][r]);
        #pragma unroll
        for (int off=1; off<16; off<<=1) mx = fmaxf(mx, __shfl_xor(mx, off, 64));
        float sm = 0.f;
        #pragma unroll
        for (int nt=0; nt<14; nt++) {
            float p = (nt*16 + lc < 197) ? expf((sc[nt][r] - mx) * 0.125f) : 0.f;
            sc[nt][r] = p; sm += p;
        }
        #pragma unroll
        for (int off=1; off<16; off<<=1) sm += __shfl_xor(sm, off, 64);
        float inv = 1.f / sm;
        int prow = w*16 + lg*4 + r;
        #pragma unroll
        for (int nt=0; nt<14; nt++)
            KP[prow*232 + nt*16 + lc] = (__bf16)(sc[nt][r] * inv);
    }

    v4f ov[4];
    #pragma unroll
    for (int nt=0; nt<4; nt++) ov[nt] = fzero4();
    #pragma unroll
    for (int ks=0; ks<7; ks++) {
        v8bf a = *(const v8bf*)&KP[(w*16 + lc)*232 + ks*32 + lg*8];
        #pragma unroll
        for (int nt=0; nt<4; nt++) {
            v8bf b = *(const v8bf*)&Vsh[(nt*16 + lc)*232 + ks*32 + lg*8];
            ov[nt] = __builtin_amdgcn_mfma_f32_16x16x32_bf16(a, b, ov[nt], 0,0,0);
        }
    }
    #pragma unroll
    for (int nt=0; nt<4; nt++)
        #pragma unroll
        for (int r=0; r<4; r++) {
            int qrow = q0 + w*16 + lg*4 + r;
            if (qrow < 197) {
                float* p = resid + ((size_t)n*197 + qrow)*768 + h*64 + nt*16 + lc;
                *p += ov[nt][r];
            }
        }
}

// ---------------------------------------------------------------------------
extern "C" void kernel_launch(void* const* d_in, const int* in_sizes, int n_in,
                              void* d_out, int out_size, void* d_ws, size_t ws_size,
                              hipStream_t stream) {
    const float* x    = (const float*)d_in[0];
    const float* Wp   = (const float*)d_in[1];
    const float* bp   = (const float*)d_in[2];
    const float* cls  = (const float*)d_in[3];
    const float* ln1g = (const float*)d_in[4];
    const float* ln1b = (const float*)d_in[5];
    const float* Wq   = (const float*)d_in[6];
    const float* bq   = (const float*)d_in[7];
    const float* Wk   = (const float*)d_in[8];
    const float* bk   = (const float*)d_in[9];
    const float* Wv   = (const float*)d_in[10];
    const float* bv   = (const float*)d_in[11];
    const float* ln2g = (const float*)d_in[12];
    const float* ln2b = (const float*)d_in[13];
    const float* W1   = (const float*)d_in[14];
    const float* b1   = (const float*)d_in[15];
    const float* W2   = (const float*)d_in[16];
    const float* b2   = (const float*)d_in[17];
    const float* Wh   = (const float*)d_in[18];
    const float* bh   = (const float*)d_in[19];
    float* out = (float*)d_out;

    char* p = (char*)d_ws;
    auto alloc = [&](size_t bytes) -> char* {
        char* r = p; p += (bytes + 255) & ~(size_t)255; return r;
    };
    float*  resid = (float*) alloc(12608ull*768*4);
    __bf16* xln   = (__bf16*)alloc(12608ull*768*2);
    __bf16* qb    = (__bf16*)alloc(768ull*197*64*2);
    __bf16* kb    = (__bf16*)alloc(768ull*197*64*2);
    __bf16* vTb   = (__bf16*)alloc(768ull*64*208*2);
    __bf16* h1    = (__bf16*)alloc(12608ull*3072*2);
    __bf16* Wpb   = (__bf16*)alloc(768ull*768*2);
    __bf16* Whb   = (__bf16*)alloc(1000ull*768*2);
    __bf16* Apat  = h1;    // alias: used only before the layer loop
    __bf16* Ahead = xln;   // alias: used only after the layer loop

    const size_t WSZ = 3072ull*768;           // elements in one W1/W2 layer slice
    size_t used = (size_t)(p - (char*)d_ws);
    bool full = ws_size >= used + 24ull*WSZ*2 + 1024;   // all-layers bf16 weights fit?
    __bf16* w1b;
    __bf16* w2b;
    if (full) {
        w1b = (__bf16*)alloc(24ull*WSZ*2);
        w2b = w1b + 12ull*WSZ;
    } else {
        w1b = (__bf16*)alloc(WSZ*2);
        w2b = (__bf16*)alloc(WSZ*2);
    }

    f2b_k<<<576, 256, 0, stream>>>(Wp, Wpb, 147456);
    f2b_k<<<750, 256, 0, stream>>>(Wh, Whb, 192000);
    if (full) {
        f2b_k<<<27648, 256, 0, stream>>>(W1, w1b, 7077888);
        f2b_k<<<27648, 256, 0, stream>>>(W2, w2b, 7077888);
    }
    pos_init_k<<<37824, 256, 0, stream>>>(cls, resid);
    vpad_k<<<2112, 256, 0, stream>>>(vTb);
    patchify_k<<<37632, 256, 0, stream>>>(x, Apat);
    gemm3_k<0><<<dim3(6, 98), 256, 0, stream>>>(Apat, Wpb, bp, resid, nullptr,
                                                12544, 768, 768, 12544, 768);
    for (int l = 0; l < 12; l++) {
        __bf16* w1l = full ? w1b + (size_t)l*WSZ : w1b;
        __bf16* w2l = full ? w2b + (size_t)l*WSZ : w2b;
        if (!full) {
            f2b_k<<<2304, 256, 0, stream>>>(W1 + (size_t)l*WSZ, w1l, 589824);
            f2b_k<<<2304, 256, 0, stream>>>(W2 + (size_t)l*WSZ, w2l, 589824);
        }
        ln_k<<<12608, 256, 0, stream>>>(resid, ln1g + l*768, ln1b + l*768, xln);
        qkv_k<<<dim3(197, 12), 256, 0, stream>>>(xln, Wq, bq, Wk, bk, Wv, bv,
                                                 qb, kb, vTb, l);
        attn_k<<<dim3(4, 12, 64), 256, 0, stream>>>(qb, kb, vTb, resid);
        ln_k<<<12608, 256, 0, stream>>>(resid, ln2g + l*768, ln2b + l*768, xln);
        gemm3_k<1><<<dim3(24, 99), 256, 0, stream>>>(xln, w1l, b1 + l*3072,
                                                     nullptr, h1,
                                                     12608, 3072, 768, 12608, 3072);
        gemm3_k<2><<<dim3(6, 99), 256, 0, stream>>>(h1, w2l, b2 + l*768,
                                                    resid, nullptr,
                                                    12608, 768, 3072, 12608, 768);
    }
    extract_k<<<192, 256, 0, stream>>>(resid, Ahead);
    gemm3_k<3><<<dim3(8, 1), 256, 0, stream>>>(Ahead, Whb, bh, out, nullptr,
                                               64, 1000, 768, 64, 1000);
}

// Round 5
// 4672.938 us; speedup vs baseline: 1.2309x; 1.0508x over previous
//
#include <hip/hip_runtime.h>

// ---------------------------------------------------------------------------
// ViT forward on MI355X (gfx950). Round 9 (= r8 with QKV weight-size fix):
//  - gemm3_k: BM=128 BN=128 BK=64, single-buffer LDS (r7-proven, 32KB),
//    XOR-swizzled (conflicts=0). Interior-tile fast epilogue (no per-element
//    bounds/index math) + exp-based GELU (sigmoid-form tanh approx, ~8 VALU
//    vs ~18 for erff; |err| < 4e-4 << bf16 quantization of h1).
//  - qkv_k: bf16 pre-converted weights (ws-guarded; fp32 fallback path).
//    r8 BUG FIXED: Wq/Wk/Wv are 589,824 elements each (12*12*64*64), NOT
//    7,077,888 (that was W1's count) — r8 read 12x OOB and crashed.
// ---------------------------------------------------------------------------

typedef __bf16 v8bf __attribute__((ext_vector_type(8)));
typedef __bf16 v4bf __attribute__((ext_vector_type(4)));
typedef float  v4f  __attribute__((ext_vector_type(4)));

#define DEV static __device__ __forceinline__

DEV v8bf cvt8(float4 a, float4 b) {
    v8bf r;
    r[0]=(__bf16)a.x; r[1]=(__bf16)a.y; r[2]=(__bf16)a.z; r[3]=(__bf16)a.w;
    r[4]=(__bf16)b.x; r[5]=(__bf16)b.y; r[6]=(__bf16)b.z; r[7]=(__bf16)b.w;
    return r;
}
DEV v8bf bzero8() {
    v8bf z;
    #pragma unroll
    for (int i=0;i<8;i++) z[i]=(__bf16)0.f;
    return z;
}
DEV v4f fzero4() {
    v4f z;
    #pragma unroll
    for (int i=0;i<4;i++) z[i]=0.f;
    return z;
}
// GELU, tanh-approx in sigmoid form: 0.5x(1+tanh(c(x+0.044715x^3)))
//   = x * sigmoid(2c(x+0.044715x^3)), 2c = 1.5957691216. |err|<4e-4.
DEV float gelu_f(float x) {
    float u = x * (1.5957691216f + 0.0713548163f * x * x);
    return x / (1.f + __expf(-u));
}
// async global->LDS, 16 bytes per lane; LDS dest = l + lane*16 (wave-uniform base)
DEV void async16(const __bf16* g, __bf16* l) {
    __builtin_amdgcn_global_load_lds(
        (const __attribute__((address_space(1))) void*)g,
        (__attribute__((address_space(3))) void*)l,
        16, 0, 0);
}

// ---------------------------------------------------------------------------
// fp32 -> bf16 elementwise (n4 = count/4)
__global__ void f2b_k(const float* __restrict__ s, __bf16* __restrict__ d, int n4) {
    int i = blockIdx.x*256 + threadIdx.x;
    if (i >= n4) return;
    float4 f = ((const float4*)s)[i];
    v4bf b;
    b[0]=(__bf16)f.x; b[1]=(__bf16)f.y; b[2]=(__bf16)f.z; b[3]=(__bf16)f.w;
    ((v4bf*)d)[i] = b;
}

// ---------------------------------------------------------------------------
// pre-fill residual with pos-embed (+cls on token 0).
__global__ void pos_init_k(const float* __restrict__ cls, float* __restrict__ resid) {
    int idx = blockIdx.x*256 + threadIdx.x;   // 9,682,944 exact
    int col = idx % 768; int rt = idx / 768;
    int ti = rt % 197;
    float v;
    if (ti == 0) v = cls[col];
    else {
        float e = (ti & 1) ? (float)(col - 1) : (float)col;
        float wj = expf(e * -0.011992630692677323f);   // ln(1e4)/768
        v = (ti & 1) ? cosf(ti*wj) : sinf(ti*wj);
    }
    resid[idx] = v;
}

// zero the vT padding (s in [197,208)) — ws is re-poisoned before each call
__global__ void vpad_k(__bf16* __restrict__ vT) {
    int idx = blockIdx.x*256 + threadIdx.x;   // 540,672 exact
    int a = idx/11, s = idx - a*11;
    vT[(size_t)a*208 + 197 + s] = (__bf16)0.f;
}

// ---------------------------------------------------------------------------
// patchify: x (64,3,224,224) fp32 -> Apat (12544,768) bf16
__global__ void patchify_k(const float* __restrict__ x, __bf16* __restrict__ Ap) {
    int idx = blockIdx.x*256 + threadIdx.x;   // 12544*768 exact
    int m = idx/768, kk = idx - m*768;
    int n = m/196, pp = m - n*196;
    int pi = pp/14, pj = pp - pi*14;
    int c = kk >> 8, rr = kk & 255, hi = rr >> 4, wi = rr & 15;
    Ap[idx] = (__bf16)x[((size_t)((n*3 + c)*224 + pi*16 + hi))*224 + pj*16 + wi];
}

// extract: residual token-0 rows -> Ahead (64,768) bf16
__global__ void extract_k(const float* __restrict__ resid, __bf16* __restrict__ Ah) {
    int idx = blockIdx.x*256 + threadIdx.x;   // 49152 exact
    int n = idx/768, d = idx - n*768;
    Ah[idx] = (__bf16)resid[(size_t)(n*197)*768 + d];
}

// ---------------------------------------------------------------------------
// LayerNorm over D=768: fp32 in -> bf16 out. One block per row.
__global__ __launch_bounds__(256) void ln_k(const float* __restrict__ resid,
                                            const float* __restrict__ gamma,
                                            const float* __restrict__ beta,
                                            __bf16* __restrict__ out) {
    __shared__ float red[4];
    int row = blockIdx.x, t = threadIdx.x;
    const float* xr = resid + (size_t)row*768;
    float x0 = xr[t], x1 = xr[t+256], x2 = xr[t+512];
    float s = x0+x1+x2;
    #pragma unroll
    for (int off=1; off<64; off<<=1) s += __shfl_xor(s, off, 64);
    if ((t&63)==0) red[t>>6] = s;
    __syncthreads();
    float mu = (red[0]+red[1]+red[2]+red[3]) * (1.f/768.f);
    __syncthreads();
    float d0=x0-mu, d1=x1-mu, d2=x2-mu;
    float q = d0*d0 + d1*d1 + d2*d2;
    #pragma unroll
    for (int off=1; off<64; off<<=1) q += __shfl_xor(q, off, 64);
    if ((t&63)==0) red[t>>6] = q;
    __syncthreads();
    float var = (red[0]+red[1]+red[2]+red[3]) * (1.f/768.f);
    float rs = rsqrtf(var + 1e-5f);
    __bf16* o = out + (size_t)row*768;
    o[t]     = (__bf16)(d0*rs*gamma[t]     + beta[t]);
    o[t+256] = (__bf16)(d1*rs*gamma[t+256] + beta[t+256]);
    o[t+512] = (__bf16)(d2*rs*gamma[t+512] + beta[t+512]);
}

// ---------------------------------------------------------------------------
// GEMM: C[m][n] = sum_k A[m][k]*B[n][k], A,B bf16. Tile 128x128x64.
// Single-buffer LDS (32KB -> 5 blocks/CU): stage -> sync -> compute -> sync.
// XOR swizzle: physical 16B slot p of row r holds logical slot p^(r&7).
// Epilogue: block-uniform interior fast path (no per-element bounds/index).
// EPI: 0 = +bias, patch-embed row remap (n*197+p+1), += into resid
//      1 = +bias, GELU -> bf16
//      2 = +bias, += resid fp32
//      3 = +bias -> fp32 out
template<int EPI>
__global__ __launch_bounds__(256) void gemm3_k(
    const __bf16* __restrict__ A, const __bf16* __restrict__ B,
    const float* __restrict__ bias,
    float* __restrict__ outf, __bf16* __restrict__ outb,
    int M, int N, int K, int MV, int NV)
{
    __shared__ __align__(16) __bf16 As[128*64];
    __shared__ __align__(16) __bf16 Bs[128*64];
    const int tid = threadIdx.x, lane = tid & 63, w = tid >> 6;
    const int m0 = blockIdx.y * 128, n0 = blockIdx.x * 128;
    const int rw = (w & 1) * 64, cw = (w >> 1) * 64;
    const int lg = lane >> 4, lc = lane & 15;
    const int lr = lane >> 3;
    const int lk8s = (((lane & 7) ^ lr) * 8);  // pre-swizzled source 16B slot

    v4f acc[4][4];
    #pragma unroll
    for (int i=0;i<4;i++)
        #pragma unroll
        for (int j=0;j<4;j++) acc[i][j] = fzero4();

    const int NK = K >> 6;
    // stage: A 16 chunks (4/wave), B 16 chunks (4/wave); chunk = 8 rows of 64.
    auto stage = [&](int kt) {
        #pragma unroll
        for (int i=0;i<4;i++) {
            int chunk = w*4 + i;
            int r = chunk*8 + lr;
            int gr = m0 + r; gr = gr < M ? gr : M-1;
            async16(A + (size_t)gr*K + kt + lk8s, &As[chunk*512]);
        }
        #pragma unroll
        for (int i=0;i<4;i++) {
            int chunk = w*4 + i;
            int r = chunk*8 + lr;
            int gc = n0 + r; gc = gc < N ? gc : N-1;
            async16(B + (size_t)gc*K + kt + lk8s, &Bs[chunk*512]);
        }
    };

    for (int ki = 0; ki < NK; ki++) {
        stage(ki << 6);
        __syncthreads();              // drains vmcnt+lgkm: tile ready
        #pragma unroll
        for (int ks=0; ks<2; ks++) {
            v8bf af[4], bf[4];
            #pragma unroll
            for (int i=0;i<4;i++) {
                int row = rw + i*16 + lc;
                af[i] = *(const v8bf*)&As[row*64 + (((ks*4 + lg) ^ (row & 7)) << 3)];
            }
            #pragma unroll
            for (int j=0;j<4;j++) {
                int row = cw + j*16 + lc;
                bf[j] = *(const v8bf*)&Bs[row*64 + (((ks*4 + lg) ^ (row & 7)) << 3)];
            }
            #pragma unroll
            for (int i=0;i<4;i++)
                #pragma unroll
                for (int j=0;j<4;j++)
                    acc[i][j] = __builtin_amdgcn_mfma_f32_16x16x32_bf16(
                        af[i], bf[j], acc[i][j], 0, 0, 0);
        }
        __syncthreads();              // all waves done reading before restage
    }

    const bool interior = (m0 + 127 < MV) && (n0 + 127 < NV);
    if (EPI != 0 && interior) {
        // fast path: no per-element bounds; strength-reduced addressing
        #pragma unroll
        for (int i=0;i<4;i++)
            #pragma unroll
            for (int j=0;j<4;j++) {
                int row0 = m0 + rw + i*16 + lg*4;
                int col  = n0 + cw + j*16 + lc;
                float bj = bias[col];
                if constexpr (EPI == 1) {
                    __bf16* p0 = outb + (size_t)row0*NV + col;
                    #pragma unroll
                    for (int r=0;r<4;r++)
                        p0[(size_t)r*NV] = (__bf16)gelu_f(acc[i][j][r] + bj);
                } else if constexpr (EPI == 2) {
                    float* p0 = outf + (size_t)row0*NV + col;
                    #pragma unroll
                    for (int r=0;r<4;r++)
                        p0[(size_t)r*NV] += acc[i][j][r] + bj;
                } else if constexpr (EPI == 3) {
                    float* p0 = outf + (size_t)row0*NV + col;
                    #pragma unroll
                    for (int r=0;r<4;r++)
                        p0[(size_t)r*NV] = acc[i][j][r] + bj;
                }
            }
    } else {
        #pragma unroll
        for (int i=0;i<4;i++)
            #pragma unroll
            for (int j=0;j<4;j++)
                #pragma unroll
                for (int r=0;r<4;r++) {
                    int row = m0 + rw + i*16 + lg*4 + r;
                    int col = n0 + cw + j*16 + lc;
                    if (row >= MV || col >= NV) continue;
                    float v = acc[i][j][r];
                    if constexpr (EPI == 0) {
                        int n = row / 196, p = row - n*196;
                        outf[((size_t)(n*197 + p + 1))*768 + col] += v + bias[col];
                    } else if constexpr (EPI == 1) {
                        outb[(size_t)row*NV + col] = (__bf16)gelu_f(v + bias[col]);
                    } else if constexpr (EPI == 2) {
                        outf[(size_t)row*NV + col] += v + bias[col];
                    } else {
                        outf[(size_t)row*NV + col] = v + bias[col];
                    }
                }
    }
}

// ---------------------------------------------------------------------------
// Per-head QKV projection. Grid (197 m-tiles of 64, 12 heads).
// BF16W=1: weights pre-converted to bf16 (Wq_/Wk_/Wv_ are __bf16*).
// BF16W=0: fp32 weights, converted in-kernel (fallback when ws is tight).
template<int BF16W>
__global__ __launch_bounds__(256) void qkv_k(
    const __bf16* __restrict__ xln,
    const void* __restrict__ Wq_, const float* __restrict__ bq,
    const void* __restrict__ Wk_, const float* __restrict__ bk,
    const void* __restrict__ Wv_, const float* __restrict__ bv,
    __bf16* __restrict__ qo, __bf16* __restrict__ ko, __bf16* __restrict__ vT,
    int l)
{
    constexpr int LDT = 72;
    __shared__ __align__(16) __bf16 Xs[64*LDT];
    __shared__ __align__(16) __bf16 Ws[3*64*LDT];
    const int tid = threadIdx.x, lane = tid & 63, w = tid >> 6;
    const int lg = lane >> 4, lc = lane & 15;
    const int m0 = blockIdx.x * 64, h = blockIdx.y;
    const int off = (l*12 + h) * 4096, bo = (l*12 + h) * 64;
    const float* Bm[3] = {bq + bo, bk + bo, bv + bo};

    #pragma unroll
    for (int i=0;i<2;i++) {
        int c = i*256 + tid, r = c >> 3, k8 = (c & 7) * 8;
        *(v8bf*)&Xs[r*LDT + k8] = *(const v8bf*)(xln + (size_t)(m0+r)*768 + h*64 + k8);
    }
    if constexpr (BF16W) {
        const __bf16* Wm[3] = {(const __bf16*)Wq_ + off, (const __bf16*)Wk_ + off,
                               (const __bf16*)Wv_ + off};
        #pragma unroll
        for (int mat=0; mat<3; mat++)
            #pragma unroll
            for (int i=0;i<2;i++) {
                int c = i*256 + tid, r = c >> 3, k8 = (c & 7) * 8;
                *(v8bf*)&Ws[mat*64*LDT + r*LDT + k8] =
                    *(const v8bf*)(Wm[mat] + r*64 + k8);
            }
    } else {
        const float* Wm[3] = {(const float*)Wq_ + off, (const float*)Wk_ + off,
                              (const float*)Wv_ + off};
        #pragma unroll
        for (int mat=0; mat<3; mat++)
            #pragma unroll
            for (int i=0;i<2;i++) {
                int c = i*256 + tid, r = c >> 3, k8 = (c & 7) * 8;
                const float* p = Wm[mat] + r*64 + k8;
                *(v8bf*)&Ws[mat*64*LDT + r*LDT + k8] =
                    cvt8(*(const float4*)p, *(const float4*)(p+4));
            }
    }
    __syncthreads();

    v8bf af[2];
    af[0] = *(const v8bf*)&Xs[(w*16 + lc)*LDT + lg*8];
    af[1] = *(const v8bf*)&Xs[(w*16 + lc)*LDT + 32 + lg*8];
    v4f acc[3][4];
    #pragma unroll
    for (int m=0;m<3;m++)
        #pragma unroll
        for (int j=0;j<4;j++) acc[m][j] = fzero4();

    #pragma unroll
    for (int mat=0; mat<3; mat++)
        #pragma unroll
        for (int ks=0; ks<2; ks++)
            #pragma unroll
            for (int nt=0; nt<4; nt++) {
                v8bf bf = *(const v8bf*)&Ws[mat*64*LDT + (nt*16 + lc)*LDT + ks*32 + lg*8];
                acc[mat][nt] = __builtin_amdgcn_mfma_f32_16x16x32_bf16(
                    af[ks], bf, acc[mat][nt], 0, 0, 0);
            }

    #pragma unroll
    for (int mat=0; mat<3; mat++)
        #pragma unroll
        for (int nt=0; nt<4; nt++)
            #pragma unroll
            for (int r=0; r<4; r++) {
                int row = m0 + w*16 + lg*4 + r;
                int n = row / 197, s = row - n*197;
                int o = nt*16 + lc;
                float v = acc[mat][nt][r] + Bm[mat][o];
                if (mat == 0)
                    qo[(size_t)((n*12 + h)*197 + s)*64 + o] = (__bf16)v;
                else if (mat == 1)
                    ko[(size_t)((n*12 + h)*197 + s)*64 + o] = (__bf16)v;
                else
                    vT[(size_t)((n*12 + h)*64 + o)*208 + s] = (__bf16)v;
            }
}

// ---------------------------------------------------------------------------
// Attention for one (n,h,qtile-of-64). S=197 padded to 224 keys.
__global__ __launch_bounds__(256) void attn_k(
    const __bf16* __restrict__ q, const __bf16* __restrict__ k,
    const __bf16* __restrict__ vT, float* __restrict__ resid)
{
    __shared__ __align__(16) __bf16 KP[224*72];    // K tile, later aliased as P
    __shared__ __align__(16) __bf16 Vsh[64*232];   // V^T tile [dh][key]
    const int tid = threadIdx.x, lane = tid & 63, w = tid >> 6;
    const int lg = lane >> 4, lc = lane & 15;
    const int q0 = blockIdx.x * 64, h = blockIdx.y, n = blockIdx.z;
    const size_t nh = n*12 + h;
    const __bf16* kg = k  + nh*197*64;
    const __bf16* vg = vT + nh*64*208;
    const __bf16* qg = q  + nh*197*64;
    const v8bf z8 = bzero8();

    #pragma unroll
    for (int i=0;i<7;i++) {
        int c = i*256 + tid, r = c >> 3, k8 = (c & 7) * 8;
        v8bf val = (r < 197) ? *(const v8bf*)(kg + r*64 + k8) : z8;
        *(v8bf*)&KP[r*72 + k8] = val;
    }
    #pragma unroll
    for (int i=0;i<7;i++) {
        int c = i*256 + tid, r = c/28, s8 = (c - r*28) * 8;
        v8bf val = (s8 < 208) ? *(const v8bf*)(vg + r*208 + s8) : z8;
        *(v8bf*)&Vsh[r*232 + s8] = val;
    }
    int qs = q0 + w*16 + lc; qs = qs < 197 ? qs : 196;
    v8bf aq0 = *(const v8bf*)(qg + qs*64 + lg*8);
    v8bf aq1 = *(const v8bf*)(qg + qs*64 + 32 + lg*8);
    __syncthreads();

    v4f sc[14];
    #pragma unroll
    for (int nt=0; nt<14; nt++) sc[nt] = fzero4();
    #pragma unroll
    for (int nt=0; nt<14; nt++) {
        v8bf b0 = *(const v8bf*)&KP[(nt*16 + lc)*72 + lg*8];
        v8bf b1 = *(const v8bf*)&KP[(nt*16 + lc)*72 + 32 + lg*8];
        sc[nt] = __builtin_amdgcn_mfma_f32_16x16x32_bf16(aq0, b0, sc[nt], 0,0,0);
        sc[nt] = __builtin_amdgcn_mfma_f32_16x16x32_bf16(aq1, b1, sc[nt], 0,0,0);
    }
    __syncthreads();

    #pragma unroll
    for (int r=0; r<4; r++) {
        float mx = -1e30f;
        #pragma unroll
        for (int nt=0; nt<14; nt++)
            if (nt*16 + lc < 197) mx = fmaxf(mx, sc[nt][r]);
        #pragma unroll
        for (int off=1; off<16; off<<=1) mx = fmaxf(mx, __shfl_xor(mx, off, 64));
        float sm = 0.f;
        #pragma unroll
        for (int nt=0; nt<14; nt++) {
            float p = (nt*16 + lc < 197) ? expf((sc[nt][r] - mx) * 0.125f) : 0.f;
            sc[nt][r] = p; sm += p;
        }
        #pragma unroll
        for (int off=1; off<16; off<<=1) sm += __shfl_xor(sm, off, 64);
        float inv = 1.f / sm;
        int prow = w*16 + lg*4 + r;
        #pragma unroll
        for (int nt=0; nt<14; nt++)
            KP[prow*232 + nt*16 + lc] = (__bf16)(sc[nt][r] * inv);
    }

    v4f ov[4];
    #pragma unroll
    for (int nt=0; nt<4; nt++) ov[nt] = fzero4();
    #pragma unroll
    for (int ks=0; ks<7; ks++) {
        v8bf a = *(const v8bf*)&KP[(w*16 + lc)*232 + ks*32 + lg*8];
        #pragma unroll
        for (int nt=0; nt<4; nt++) {
            v8bf b = *(const v8bf*)&Vsh[(nt*16 + lc)*232 + ks*32 + lg*8];
            ov[nt] = __builtin_amdgcn_mfma_f32_16x16x32_bf16(a, b, ov[nt], 0,0,0);
        }
    }
    #pragma unroll
    for (int nt=0; nt<4; nt++)
        #pragma unroll
        for (int r=0; r<4; r++) {
            int qrow = q0 + w*16 + lg*4 + r;
            if (qrow < 197) {
                float* p = resid + ((size_t)n*197 + qrow)*768 + h*64 + nt*16 + lc;
                *p += ov[nt][r];
            }
        }
}

// ---------------------------------------------------------------------------
extern "C" void kernel_launch(void* const* d_in, const int* in_sizes, int n_in,
                              void* d_out, int out_size, void* d_ws, size_t ws_size,
                              hipStream_t stream) {
    const float* x    = (const float*)d_in[0];
    const float* Wp   = (const float*)d_in[1];
    const float* bp   = (const float*)d_in[2];
    const float* cls  = (const float*)d_in[3];
    const float* ln1g = (const float*)d_in[4];
    const float* ln1b = (const float*)d_in[5];
    const float* Wq   = (const float*)d_in[6];
    const float* bq   = (const float*)d_in[7];
    const float* Wk   = (const float*)d_in[8];
    const float* bk   = (const float*)d_in[9];
    const float* Wv   = (const float*)d_in[10];
    const float* bv   = (const float*)d_in[11];
    const float* ln2g = (const float*)d_in[12];
    const float* ln2b = (const float*)d_in[13];
    const float* W1   = (const float*)d_in[14];
    const float* b1   = (const float*)d_in[15];
    const float* W2   = (const float*)d_in[16];
    const float* b2   = (const float*)d_in[17];
    const float* Wh   = (const float*)d_in[18];
    const float* bh   = (const float*)d_in[19];
    float* out = (float*)d_out;

    char* p = (char*)d_ws;
    auto alloc = [&](size_t bytes) -> char* {
        char* r = p; p += (bytes + 255) & ~(size_t)255; return r;
    };
    float*  resid = (float*) alloc(12608ull*768*4);
    __bf16* xln   = (__bf16*)alloc(12608ull*768*2);
    __bf16* qb    = (__bf16*)alloc(768ull*197*64*2);
    __bf16* kb    = (__bf16*)alloc(768ull*197*64*2);
    __bf16* vTb   = (__bf16*)alloc(768ull*64*208*2);
    __bf16* h1    = (__bf16*)alloc(12608ull*3072*2);
    __bf16* Wpb   = (__bf16*)alloc(768ull*768*2);
    __bf16* Whb   = (__bf16*)alloc(1000ull*768*2);
    __bf16* Apat  = h1;    // alias: used only before the layer loop
    __bf16* Ahead = xln;   // alias: used only after the layer loop

    const size_t WSZ = 3072ull*768;           // elements in one W1/W2 layer slice
    size_t used = (size_t)(p - (char*)d_ws);
    bool full = ws_size >= used + 24ull*WSZ*2 + 1024;   // all-layers bf16 weights fit?
    __bf16* w1b;
    __bf16* w2b;
    if (full) {
        w1b = (__bf16*)alloc(24ull*WSZ*2);
        w2b = w1b + 12ull*WSZ;
    } else {
        w1b = (__bf16*)alloc(WSZ*2);
        w2b = (__bf16*)alloc(WSZ*2);
    }
    // all-layers QKV weights as bf16: 12 layers * 12 heads * 64*64 = 589,824
    // elements per matrix (1.18 MB bf16 each).
    const size_t QW = 589824ull;
    size_t used1 = (size_t)(p - (char*)d_ws);
    bool qfull = ws_size >= used1 + 3ull*QW*2 + 1024;
    __bf16 *wqb = nullptr, *wkb = nullptr, *wvb = nullptr;
    if (qfull) {
        wqb = (__bf16*)alloc(QW*2);
        wkb = (__bf16*)alloc(QW*2);
        wvb = (__bf16*)alloc(QW*2);
    }

    f2b_k<<<576, 256, 0, stream>>>(Wp, Wpb, 147456);
    f2b_k<<<750, 256, 0, stream>>>(Wh, Whb, 192000);
    if (full) {
        f2b_k<<<27648, 256, 0, stream>>>(W1, w1b, 7077888);
        f2b_k<<<27648, 256, 0, stream>>>(W2, w2b, 7077888);
    }
    if (qfull) {
        f2b_k<<<576, 256, 0, stream>>>(Wq, wqb, 147456);   // 589824/4
        f2b_k<<<576, 256, 0, stream>>>(Wk, wkb, 147456);
        f2b_k<<<576, 256, 0, stream>>>(Wv, wvb, 147456);
    }
    pos_init_k<<<37824, 256, 0, stream>>>(cls, resid);
    vpad_k<<<2112, 256, 0, stream>>>(vTb);
    patchify_k<<<37632, 256, 0, stream>>>(x, Apat);
    gemm3_k<0><<<dim3(6, 98), 256, 0, stream>>>(Apat, Wpb, bp, resid, nullptr,
                                                12544, 768, 768, 12544, 768);
    for (int l = 0; l < 12; l++) {
        __bf16* w1l = full ? w1b + (size_t)l*WSZ : w1b;
        __bf16* w2l = full ? w2b + (size_t)l*WSZ : w2b;
        if (!full) {
            f2b_k<<<2304, 256, 0, stream>>>(W1 + (size_t)l*WSZ, w1l, 589824);
            f2b_k<<<2304, 256, 0, stream>>>(W2 + (size_t)l*WSZ, w2l, 589824);
        }
        ln_k<<<12608, 256, 0, stream>>>(resid, ln1g + l*768, ln1b + l*768, xln);
        if (qfull)
            qkv_k<1><<<dim3(197, 12), 256, 0, stream>>>(xln, wqb, bq, wkb, bk,
                                                        wvb, bv, qb, kb, vTb, l);
        else
            qkv_k<0><<<dim3(197, 12), 256, 0, stream>>>(xln, Wq, bq, Wk, bk,
                                                        Wv, bv, qb, kb, vTb, l);
        attn_k<<<dim3(4, 12, 64), 256, 0, stream>>>(qb, kb, vTb, resid);
        ln_k<<<12608, 256, 0, stream>>>(resid, ln2g + l*768, ln2b + l*768, xln);
        gemm3_k<1><<<dim3(24, 99), 256, 0, stream>>>(xln, w1l, b1 + l*3072,
                                                     nullptr, h1,
                                                     12608, 3072, 768, 12608, 3072);
        gemm3_k<2><<<dim3(6, 99), 256, 0, stream>>>(h1, w2l, b2 + l*768,
                                                    resid, nullptr,
                                                    12608, 768, 3072, 12608, 768);
    }
    extract_k<<<192, 256, 0, stream>>>(resid, Ahead);
    gemm3_k<3><<<dim3(8, 1), 256, 0, stream>>>(Ahead, Whb, bh, out, nullptr,
                                               64, 1000, 768, 64, 1000);
}